// Round 1
// baseline (145.359 us; speedup 1.0000x reference)
//
#include <hip/hip_runtime.h>
#include <math.h>

#define DD   41     // depth bins
#define FHh  32
#define FWw  88
#define CC   64     // camera channels
#define CH   32     // channels per colpool half
#define NXx  200
#define NZz  200
#define NCH  (DD + CC)              // 105
#define PLANE ((size_t)FHh * FWw)   // 2816
#define VOXB (NZz * NXx)            // 40000 floats per (b,c) slab
// x: (B, 105, 32, 88) fp32 ; out: (B, 64, 200, 200) fp32

// ---------- Kernel Z: zero the whole output (grid-stride float4) ----------
__global__ __launch_bounds__(256) void lss_zero(float4* __restrict__ o4, int nq)
{
    float4 z = make_float4(0.f, 0.f, 0.f, 0.f);
    int stride = gridDim.x * 256;
    for (int i = blockIdx.x * 256 + threadIdx.x; i < nq; i += stride) o4[i] = z;
}

// ---------- Kernel F: per-(b,w,c-half) column pool + direct atomic scatter ----------
// Replaces the old 3-kernel pipeline (colpool -> rowbuild -> fixup). Device-scope
// float atomicAdd handles arbitrary geometry (row collisions, per-w iz mismatches)
// honestly, so the owner/collision/overflow machinery and the P/V round trip vanish.
__global__ __launch_bounds__(256) void lss_fused(
    const float* __restrict__ x,
    const float* __restrict__ intrins,
    const float* __restrict__ post_rots,
    const float* __restrict__ post_trans,
    float* __restrict__ out)
{
    __shared__ float Wt[DD][FHh + 1];   // logits -> masked softmax weights
    __shared__ float F4s[FHh][36];      // half-F [h][c], row 36 floats (16B-aligned)
    __shared__ float Mi[18];            // inv(post_rots), inv(intrins)
    __shared__ float pm[8][FHh + 1];    // partial max / sum
    __shared__ int   Vtmp[DD];          // iz*NXx+ix per d, or -1

    int blk   = blockIdx.x;
    int chalf = blk & 1;
    int w     = (blk >> 1) % FWw;
    int b     = blk / (2 * FWw);
    int t     = threadIdx.x;
    const float* xb = x + (size_t)b * NCH * PLANE + w;

    for (int idx = t; idx < DD * FHh; idx += 256) {
        int d = idx >> 5, h = idx & 31;
        Wt[d][h] = xb[((size_t)d * FHh + h) * FWw];
    }
    for (int idx = t; idx < FHh * CH; idx += 256) {
        int c = idx & 31, h = idx >> 5;
        F4s[h][c] = xb[((size_t)(DD + chalf * CH + c) * FHh + h) * FWw];
    }
    if (t >= 64 && t < 64 + DD) Vtmp[t - 64] = -1;
    if (t == 0) {
        #pragma clang fp contract(off)
        // adjugate inverse; exact for identity rots / triangular K -> entries
        // are single correctly-rounded divisions, matching jnp.linalg.inv.
        for (int m = 0; m < 2; ++m) {
            const float* A = (m == 0 ? post_rots : intrins) + b * 9;
            float* O = Mi + m * 9;
            float a = A[0], bb = A[1], c = A[2];
            float d = A[3], e  = A[4], f = A[5];
            float g = A[6], h  = A[7], i = A[8];
            float det = a * (e * i - f * h) - bb * (d * i - f * g) + c * (d * h - e * g);
            O[0] = (e * i - f * h) / det;
            O[1] = (c * h - bb * i) / det;
            O[2] = (bb * f - c * e) / det;
            O[3] = (f * g - d * i) / det;
            O[4] = (a * i - c * g) / det;
            O[5] = (c * d - a * f) / det;
            O[6] = (d * h - e * g) / det;
            O[7] = (bb * g - a * h) / det;
            O[8] = (a * e - bb * d) / det;
        }
    }
    __syncthreads();

    // ---- parallel softmax: thread (h = t&31, l = t>>5) owns d = l+8k ----
    int h = t & 31, l = t >> 5;
    float e_[6];
    {
        float pmax = -INFINITY;
        for (int d = l; d < DD; d += 8) pmax = fmaxf(pmax, Wt[d][h]);
        pm[l][h] = pmax;
    }
    __syncthreads();
    float mx = -INFINITY;
    for (int j = 0; j < 8; ++j) mx = fmaxf(mx, pm[j][h]);
    __syncthreads();
    {
        #pragma clang fp contract(off)
        float psum = 0.0f;
        int k = 0;
        for (int d = l; d < DD; d += 8, ++k) {
            float e = expf(Wt[d][h] - mx);
            e_[k] = e; psum += e;
        }
        pm[l][h] = psum;
    }
    __syncthreads();
    float s = 0.0f;
    for (int j = 0; j < 8; ++j) s += pm[j][h];

    // ---- geometry per (d,h), honest mask ----
    {
        #pragma clang fp contract(off)
        float xs = (float)((double)w * 703.0 / 87.0);   // linspace(0,703,88)
        float ys = (float)((double)h * 255.0 / 31.0);   // linspace(0,255,32)
        float tx = post_trans[b * 3 + 0];
        float ty = post_trans[b * 3 + 1];
        float tz = post_trans[b * 3 + 2];
        int k = 0;
        for (int d = l; d < DD; d += 8, ++k) {
            float z  = 4.0f + (float)d;
            float px = xs - tx, py = ys - ty, pz = z - tz;
            float rx = Mi[0] * px + Mi[1] * py + Mi[2] * pz;
            float ry = Mi[3] * px + Mi[4] * py + Mi[5] * pz;
            float rz = Mi[6] * px + Mi[7] * py + Mi[8] * pz;
            float qx = rx * rz, qy = ry * rz, qz = rz;
            float gx = Mi[ 9] * qx + Mi[10] * qy + Mi[11] * qz;
            float gy = Mi[12] * qx + Mi[13] * qy + Mi[14] * qz;
            float gz = Mi[15] * qx + Mi[16] * qy + Mi[17] * qz;
            float cx = (gx + 50.0f) / 0.5f;
            float cy = (gy + 10.0f) / 20.0f;
            float cz = gz / 0.25f;
            int ix = (int)cx;   // trunc == numpy astype(int32)
            int iy = (int)cy;
            int iz = (int)cz;
            bool kept = (ix >= 0) & (ix < NXx) & (iy == 0) & (iz >= 0) & (iz < NZz);
            if (kept) {
                Wt[d][h] = e_[k] / s;
                Vtmp[d] = iz * NXx + ix;   // ix,iz depend only on (w,d): same-value
                                           // across h threads -> benign race
            } else {
                Wt[d][h] = 0.0f;
            }
        }
    }
    __syncthreads();

    // ---- pool over h, then scatter straight into out with device atomics ----
    // out[b][c][iz][ix] = base_b + c*VOXB + (iz*NXx+ix); Vtmp[d] is the latter.
    float* ob = out + ((size_t)b * CC + chalf * CH) * VOXB;
    {
        int c4 = t & 7;
        for (int d = t >> 3; d < DD; d += 32) {
            int v = Vtmp[d];
            if (v < 0) continue;        // fully masked depth: contributes nothing
            float4 acc = make_float4(0.f, 0.f, 0.f, 0.f);
            for (int hh = 0; hh < FHh; ++hh) {
                float wtv = Wt[d][hh];
                float4 fv = *(const float4*)&F4s[hh][c4 * 4];
                acc.x += wtv * fv.x; acc.y += wtv * fv.y;
                acc.z += wtv * fv.z; acc.w += wtv * fv.w;
            }
            float* p0 = ob + (size_t)(c4 * 4) * VOXB + v;
            atomicAdd(p0,             acc.x);
            atomicAdd(p0 + VOXB,      acc.y);
            atomicAdd(p0 + 2 * VOXB,  acc.z);
            atomicAdd(p0 + 3 * VOXB,  acc.w);
        }
    }
}

extern "C" void kernel_launch(void* const* d_in, const int* in_sizes, int n_in,
                              void* d_out, int out_size, void* d_ws, size_t ws_size,
                              hipStream_t stream)
{
    const float* x          = (const float*)d_in[0];
    const float* intrins    = (const float*)d_in[1];
    const float* post_rots  = (const float*)d_in[2];
    const float* post_trans = (const float*)d_in[3];
    float* out = (float*)d_out;

    int B = in_sizes[0] / (NCH * (int)PLANE);

    // out_size is an element count (B deduced the same way from in_sizes[0]).
    int out_quads = out_size / 4;
    int zb = (out_quads + 255) / 256;
    if (zb > 2048) zb = 2048;

    lss_zero <<<zb, 256, 0, stream>>>((float4*)out, out_quads);
    lss_fused<<<B * FWw * 2, 256, 0, stream>>>(x, intrins, post_rots, post_trans, out);
}

// Round 2
// 124.233 us; speedup vs baseline: 1.1701x; 1.1701x over previous
//
#include <hip/hip_runtime.h>
#include <math.h>

#define DD   41     // depth bins
#define FHh  32
#define FWw  88
#define CC   64     // camera channels
#define CH   32     // channels per colpool half
#define CG8  8      // channels per row block
#define NXx  200
#define NZz  200
#define NCH  (DD + CC)              // 105
#define PLANE ((size_t)FHh * FWw)   // 2816
#define NE   (DD * FWw)             // 3608 (d,w) entries per batch
// x: (B, 105, 32, 88) fp32 ; out: (B, 64, 200, 200) fp32

// ---------- Kernel A: per-(b,w,c-half) column softmax + pool -> P, V ----------
__global__ __launch_bounds__(256) void lss_colpool(
    const float* __restrict__ x,
    const float* __restrict__ intrins,
    const float* __restrict__ post_rots,
    const float* __restrict__ post_trans,
    float* __restrict__ P, int* __restrict__ V)
{
    __shared__ float Wt[DD][FHh + 1];   // logits -> masked softmax weights
    __shared__ float F4s[FHh][36];      // half-F [h][c], row 36 floats (16B-aligned)
    __shared__ float Mi[18];            // inv(post_rots), inv(intrins)
    __shared__ float pm[8][FHh + 1];    // partial max / sum
    __shared__ int   Vtmp[DD];          // iz*NXx+ix per d, or -1

    int blk   = blockIdx.x;
    int chalf = blk & 1;
    int w     = (blk >> 1) % FWw;
    int b     = blk / (2 * FWw);
    int t     = threadIdx.x;
    const float* xb = x + (size_t)b * NCH * PLANE + w;

    for (int idx = t; idx < DD * FHh; idx += 256) {
        int d = idx >> 5, h = idx & 31;
        Wt[d][h] = xb[((size_t)d * FHh + h) * FWw];
    }
    for (int idx = t; idx < FHh * CH; idx += 256) {
        int c = idx & 31, h = idx >> 5;
        F4s[h][c] = xb[((size_t)(DD + chalf * CH + c) * FHh + h) * FWw];
    }
    if (t >= 64 && t < 64 + DD) Vtmp[t - 64] = -1;
    if (t == 0) {
        #pragma clang fp contract(off)
        // adjugate inverse; exact for identity rots / triangular K -> entries
        // are single correctly-rounded divisions, matching jnp.linalg.inv.
        for (int m = 0; m < 2; ++m) {
            const float* A = (m == 0 ? post_rots : intrins) + b * 9;
            float* O = Mi + m * 9;
            float a = A[0], bb = A[1], c = A[2];
            float d = A[3], e  = A[4], f = A[5];
            float g = A[6], h  = A[7], i = A[8];
            float det = a * (e * i - f * h) - bb * (d * i - f * g) + c * (d * h - e * g);
            O[0] = (e * i - f * h) / det;
            O[1] = (c * h - bb * i) / det;
            O[2] = (bb * f - c * e) / det;
            O[3] = (f * g - d * i) / det;
            O[4] = (a * i - c * g) / det;
            O[5] = (c * d - a * f) / det;
            O[6] = (d * h - e * g) / det;
            O[7] = (bb * g - a * h) / det;
            O[8] = (a * e - bb * d) / det;
        }
    }
    __syncthreads();

    // ---- parallel softmax: thread (h = t&31, l = t>>5) owns d = l+8k ----
    int h = t & 31, l = t >> 5;
    float e_[6];
    {
        float pmax = -INFINITY;
        for (int d = l; d < DD; d += 8) pmax = fmaxf(pmax, Wt[d][h]);
        pm[l][h] = pmax;
    }
    __syncthreads();
    float mx = -INFINITY;
    for (int j = 0; j < 8; ++j) mx = fmaxf(mx, pm[j][h]);
    __syncthreads();
    {
        #pragma clang fp contract(off)
        float psum = 0.0f;
        int k = 0;
        for (int d = l; d < DD; d += 8, ++k) {
            float e = expf(Wt[d][h] - mx);
            e_[k] = e; psum += e;
        }
        pm[l][h] = psum;
    }
    __syncthreads();
    float s = 0.0f;
    for (int j = 0; j < 8; ++j) s += pm[j][h];

    // ---- geometry per (d,h), honest mask ----
    {
        #pragma clang fp contract(off)
        float xs = (float)((double)w * 703.0 / 87.0);   // linspace(0,703,88)
        float ys = (float)((double)h * 255.0 / 31.0);   // linspace(0,255,32)
        float tx = post_trans[b * 3 + 0];
        float ty = post_trans[b * 3 + 1];
        float tz = post_trans[b * 3 + 2];
        int k = 0;
        for (int d = l; d < DD; d += 8, ++k) {
            float z  = 4.0f + (float)d;
            float px = xs - tx, py = ys - ty, pz = z - tz;
            float rx = Mi[0] * px + Mi[1] * py + Mi[2] * pz;
            float ry = Mi[3] * px + Mi[4] * py + Mi[5] * pz;
            float rz = Mi[6] * px + Mi[7] * py + Mi[8] * pz;
            float qx = rx * rz, qy = ry * rz, qz = rz;
            float gx = Mi[ 9] * qx + Mi[10] * qy + Mi[11] * qz;
            float gy = Mi[12] * qx + Mi[13] * qy + Mi[14] * qz;
            float gz = Mi[15] * qx + Mi[16] * qy + Mi[17] * qz;
            float cx = (gx + 50.0f) / 0.5f;
            float cy = (gy + 10.0f) / 20.0f;
            float cz = gz / 0.25f;
            int ix = (int)cx;   // trunc == numpy astype(int32)
            int iy = (int)cy;
            int iz = (int)cz;
            bool kept = (ix >= 0) & (ix < NXx) & (iy == 0) & (iz >= 0) & (iz < NZz);
            if (kept) {
                Wt[d][h] = e_[k] / s;
                Vtmp[d] = iz * NXx + ix;   // (ix,iz) depend only on (w,d) here:
                                           // same-value across h -> benign race
            } else {
                Wt[d][h] = 0.0f;
            }
        }
    }
    __syncthreads();

    // ---- pool: P[b][d*FWw+w][c] = sum_h Wt[d][h]*F[h][c] ----
    float* Pb = P + ((size_t)b * NE) * CC + chalf * CH;
    {
        int c4 = t & 7;
        for (int d = t >> 3; d < DD; d += 32) {
            float4 acc = make_float4(0.f, 0.f, 0.f, 0.f);
            for (int hh = 0; hh < FHh; ++hh) {
                float wtv = Wt[d][hh];
                float4 fv = *(const float4*)&F4s[hh][c4 * 4];
                acc.x += wtv * fv.x; acc.y += wtv * fv.y;
                acc.z += wtv * fv.z; acc.w += wtv * fv.w;
            }
            *(float4*)&Pb[((size_t)d * FWw + w) * CC + c4 * 4] = acc;
        }
    }
    if (chalf == 0 && t < DD) V[(size_t)b * NE + (size_t)t * FWw + w] = Vtmp[t];
}

// ---------- Kernel B: complete-coverage row writer ----------
// One block per (b, iz, cg): scan the full V slab for entries landing in row iz,
// accumulate their P channels into an LDS row, write the row once (zeros incl.).
// Fully general: multi-d collisions and per-w iz mismatches need no fixup pass,
// and the output needs no zero-fill and no global atomics.
__global__ __launch_bounds__(256) void lss_rows(
    const float* __restrict__ P, const int* __restrict__ V,
    float* __restrict__ out)
{
    __shared__ float acc[CG8][NXx + 4];  // 8 ch x padded row (16B-aligned rows)
    __shared__ int   Vs[NE];             // 14.4 KB: whole V slab for this b

    int blk = blockIdx.x;
    int cg  = blk & 7;
    int bi  = blk >> 3;
    int iz  = bi % NZz;
    int b   = bi / NZz;
    int t   = threadIdx.x;

    for (int i = t; i < CG8 * (NXx + 4); i += 256) ((float*)acc)[i] = 0.0f;
    for (int i = t; i < NE; i += 256) Vs[i] = V[(size_t)b * NE + i];
    __syncthreads();

    int base = iz * NXx;
    const float* Pb = P + (size_t)b * NE * CC + cg * CG8;
    for (int i = t; i < NE; i += 256) {
        unsigned r = (unsigned)(Vs[i] - base);   // V=-1 wraps huge -> no match
        if (r < NXx) {
            const float4* p4 = (const float4*)&Pb[(size_t)i * CC];
            float4 v0 = p4[0], v1 = p4[1];
            int ix = (int)r;
            atomicAdd(&acc[0][ix], v0.x);
            atomicAdd(&acc[1][ix], v0.y);
            atomicAdd(&acc[2][ix], v0.z);
            atomicAdd(&acc[3][ix], v0.w);
            atomicAdd(&acc[4][ix], v1.x);
            atomicAdd(&acc[5][ix], v1.y);
            atomicAdd(&acc[6][ix], v1.z);
            atomicAdd(&acc[7][ix], v1.w);
        }
    }
    __syncthreads();

    for (int i = t; i < CG8 * (NXx / 4); i += 256) {
        int c = i / (NXx / 4), q = i - c * (NXx / 4);
        float4 vv = make_float4(acc[c][q * 4 + 0], acc[c][q * 4 + 1],
                                acc[c][q * 4 + 2], acc[c][q * 4 + 3]);
        *(float4*)(out + (((size_t)(b * CC + cg * CG8 + c)) * NZz + iz) * NXx
                   + q * 4) = vv;
    }
}

extern "C" void kernel_launch(void* const* d_in, const int* in_sizes, int n_in,
                              void* d_out, int out_size, void* d_ws, size_t ws_size,
                              hipStream_t stream)
{
    const float* x          = (const float*)d_in[0];
    const float* intrins    = (const float*)d_in[1];
    const float* post_rots  = (const float*)d_in[2];
    const float* post_trans = (const float*)d_in[3];
    float* out = (float*)d_out;

    int B = in_sizes[0] / (NCH * (int)PLANE);

    size_t off = 0;
    auto alloc = [&](size_t bytes) {
        void* p = (char*)d_ws + off;
        off = (off + bytes + 255) & ~(size_t)255;
        return p;
    };
    float* P = (float*)alloc((size_t)B * NE * CC * sizeof(float));  // 3.7 MB
    int*   V = (int*)  alloc((size_t)B * NE * sizeof(int));         // 58 KB

    lss_colpool<<<B * FWw * 2, 256, 0, stream>>>(x, intrins, post_rots, post_trans,
                                                 P, V);
    lss_rows<<<B * NZz * 8, 256, 0, stream>>>(P, V, out);
}

// Round 3
// 98.680 us; speedup vs baseline: 1.4730x; 1.2589x over previous
//
#include <hip/hip_runtime.h>
#include <math.h>

#define DD   41     // depth bins
#define FHh  32
#define FWw  88
#define CC   64     // camera channels
#define CG8  8      // channels per rowbuild block
#define NXx  200
#define NZz  200
#define NCH  (DD + CC)              // 105
#define PLANE ((size_t)FHh * FWw)   // 2816
#define NE   (DD * FWw)             // 3608
#define DCAP 4
#define OVCAP 4096
// x: (B, 105, 32, 88) fp32 ; out: (B, 64, 200, 200) fp32

// ---------- Kernel A: per-(b,w) column pool (all 64 ch) + output zero-fill ----------
// vs round-0: the two chalf blocks are merged -> logits loaded once, softmax
// computed once, 352 blocks instead of 704. Rowbuild/fixup unchanged.
__global__ __launch_bounds__(256) void lss_colpool(
    const float* __restrict__ x,
    const float* __restrict__ intrins,
    const float* __restrict__ post_rots,
    const float* __restrict__ post_trans,
    float* __restrict__ P, int* __restrict__ V,
    int* __restrict__ rowcnt8, int* __restrict__ ovcnt,
    float* __restrict__ out, int out_quads)
{
    __shared__ float Wt[DD][FHh + 1];   // logits -> masked softmax weights
    __shared__ float F4s[FHh][68];      // F [h][c] all 64 ch, padded row
    __shared__ float Mi[18];            // inv(post_rots), inv(intrins)
    __shared__ float pm[8][FHh + 1];    // partial max / sum
    __shared__ int   Vtmp[DD];

    int blk = blockIdx.x;
    int w   = blk % FWw;
    int b   = blk / FWw;
    int t   = threadIdx.x;
    const float* xb = x + (size_t)b * NCH * PLANE + w;

    for (int idx = t; idx < DD * FHh; idx += 256) {
        int d = idx >> 5, h = idx & 31;
        Wt[d][h] = xb[((size_t)d * FHh + h) * FWw];
    }
    for (int idx = t; idx < FHh * CC; idx += 256) {
        int c = idx & 63, h = idx >> 6;
        F4s[h][c] = xb[((size_t)(DD + c) * FHh + h) * FWw];
    }
    if (t >= 64 && t < 64 + DD) Vtmp[t - 64] = -1;
    if (t == 0) {
        #pragma clang fp contract(off)
        // adjugate inverse; exact for identity rots / triangular K -> entries
        // are single correctly-rounded divisions, matching jnp.linalg.inv.
        for (int m = 0; m < 2; ++m) {
            const float* A = (m == 0 ? post_rots : intrins) + b * 9;
            float* O = Mi + m * 9;
            float a = A[0], bb = A[1], c = A[2];
            float d = A[3], e  = A[4], f = A[5];
            float g = A[6], h  = A[7], i = A[8];
            float det = a * (e * i - f * h) - bb * (d * i - f * g) + c * (d * h - e * g);
            O[0] = (e * i - f * h) / det;
            O[1] = (c * h - bb * i) / det;
            O[2] = (bb * f - c * e) / det;
            O[3] = (f * g - d * i) / det;
            O[4] = (a * i - c * g) / det;
            O[5] = (c * d - a * f) / det;
            O[6] = (d * h - e * g) / det;
            O[7] = (bb * g - a * h) / det;
            O[8] = (a * e - bb * d) / det;
        }
    }
    __syncthreads();

    // ---- parallel softmax: thread (h = t&31, l = t>>5) owns d = l+8k ----
    int h = t & 31, l = t >> 5;
    float e_[6];
    {
        float pmax = -INFINITY;
        for (int d = l; d < DD; d += 8) pmax = fmaxf(pmax, Wt[d][h]);
        pm[l][h] = pmax;
    }
    __syncthreads();
    float mx = -INFINITY;
    for (int j = 0; j < 8; ++j) mx = fmaxf(mx, pm[j][h]);
    __syncthreads();
    {
        #pragma clang fp contract(off)
        float psum = 0.0f;
        int k = 0;
        for (int d = l; d < DD; d += 8, ++k) {
            float e = expf(Wt[d][h] - mx);
            e_[k] = e; psum += e;
        }
        pm[l][h] = psum;
    }
    __syncthreads();
    float s = 0.0f;
    for (int j = 0; j < 8; ++j) s += pm[j][h];

    // ---- geometry per (d,h), honest mask ----
    {
        #pragma clang fp contract(off)
        float xs = (float)((double)w * 703.0 / 87.0);   // linspace(0,703,88)
        float ys = (float)((double)h * 255.0 / 31.0);   // linspace(0,255,32)
        float tx = post_trans[b * 3 + 0];
        float ty = post_trans[b * 3 + 1];
        float tz = post_trans[b * 3 + 2];
        int k = 0;
        for (int d = l; d < DD; d += 8, ++k) {
            float z  = 4.0f + (float)d;
            float px = xs - tx, py = ys - ty, pz = z - tz;
            float rx = Mi[0] * px + Mi[1] * py + Mi[2] * pz;
            float ry = Mi[3] * px + Mi[4] * py + Mi[5] * pz;
            float rz = Mi[6] * px + Mi[7] * py + Mi[8] * pz;
            float qx = rx * rz, qy = ry * rz, qz = rz;
            float gx = Mi[ 9] * qx + Mi[10] * qy + Mi[11] * qz;
            float gy = Mi[12] * qx + Mi[13] * qy + Mi[14] * qz;
            float gz = Mi[15] * qx + Mi[16] * qy + Mi[17] * qz;
            float cx = (gx + 50.0f) / 0.5f;
            float cy = (gy + 10.0f) / 20.0f;
            float cz = gz / 0.25f;
            int ix = (int)cx;   // trunc == numpy astype(int32)
            int iy = (int)cy;
            int iz = (int)cz;
            bool kept = (ix >= 0) & (ix < NXx) & (iy == 0) & (iz >= 0) & (iz < NZz);
            if (kept) {
                Wt[d][h] = e_[k] / s;
                Vtmp[d] = iz * NXx + ix;   // (ix,iz) depend only on (w,d): all h
                                           // threads write same value -> benign
            } else {
                Wt[d][h] = 0.0f;
            }
        }
    }
    __syncthreads();

    // ---- pool: P[b][d*FWw+w][c] = sum_h Wt[d][h]*F[h][c], 16 quads x d-rows ----
    float* Pb = P + ((size_t)b * NE) * CC;
    {
        int c4 = t & 15;
        for (int d = t >> 4; d < DD; d += 16) {
            float4 acc = make_float4(0.f, 0.f, 0.f, 0.f);
            for (int hh = 0; hh < FHh; ++hh) {
                float wtv = Wt[d][hh];
                float4 fv = *(const float4*)&F4s[hh][c4 * 4];
                acc.x += wtv * fv.x; acc.y += wtv * fv.y;
                acc.z += wtv * fv.z; acc.w += wtv * fv.w;
            }
            *(float4*)&Pb[((size_t)d * FWw + w) * CC + c4 * 4] = acc;
        }
    }
    if (t < DD) V[(size_t)b * NE + (size_t)t * FWw + w] = Vtmp[t];
    if (w == 0) for (int i = t; i < NZz * 8; i += 256) rowcnt8[b * NZz * 8 + i] = 0;
    if (blk == 0 && t == 0) *ovcnt = 0;

    // ---- tail: stream the whole output to zero (grid-stride float4) ----
    {
        float4 z = make_float4(0.f, 0.f, 0.f, 0.f);
        float4* o4 = (float4*)out;
        int stride = gridDim.x * 256;
        for (int i = blk * 256 + t; i < out_quads; i += stride) o4[i] = z;
    }
}

// ---------- Kernel B: per-(b,d,8ch) row build; owner0 writes out directly ----------
__global__ __launch_bounds__(256) void lss_rowbuild(
    const float* __restrict__ P, const int* __restrict__ V,
    float* __restrict__ S, int* __restrict__ izd,
    int* __restrict__ rowcnt8, int* __restrict__ dlist8,
    int* __restrict__ ovcnt, int* __restrict__ ovlist,
    float* __restrict__ out)
{
    __shared__ float acc[CG8 * (NXx + 1)];
    __shared__ int ixw[FWw];
    __shared__ int izw[FWw];
    __shared__ int key;
    __shared__ int s_k;

    int blk = blockIdx.x;
    int cg = blk & 7;
    int bd = blk >> 3;
    int d = bd % DD;
    int b = bd / DD;
    int t = threadIdx.x;

    if (t == 0) key = 0x7fffffff;
    for (int i = t; i < CG8 * (NXx + 1); i += 256) acc[i] = 0.0f;
    __syncthreads();
    if (t < FWw) {
        int v = V[(size_t)bd * FWw + t];
        if (v >= 0) {
            int iz = v / NXx;
            izw[t] = iz; ixw[t] = v - iz * NXx;
            atomicMin(&key, (t << 16) | iz);
        } else { izw[t] = -1; ixw[t] = -1; }
    }
    __syncthreads();
    int kk = key;
    int s_iz = (kk == 0x7fffffff) ? -1 : (kk & 0xffff);  // iz of min-w kept entry
    if (cg == 0 && t == 0) izd[bd] = s_iz;
    if (s_iz < 0) return;

    int r = b * NZz + s_iz;
    if (t == 0) {
        int k = atomicAdd(&rowcnt8[r * 8 + cg], 1);
        if (k < DCAP) dlist8[(r * 8 + cg) * DCAP + k] = d;
        s_k = k;
    }
    // generic path: kept entries whose iz != s_iz go to the overflow list
    if (cg == 0 && t < FWw && izw[t] >= 0 && izw[t] != s_iz) {
        int k = atomicAdd(ovcnt, 1);
        if (k < OVCAP)
            ovlist[k] = (b << 29) | (d << 23) | (t << 16) | (ixw[t] << 8) | izw[t];
    }

    const float* Pb = P + (size_t)bd * FWw * CC + cg * CG8;
    for (int idx = t; idx < FWw * 2; idx += 256) {
        int w = idx >> 1, q = idx & 1;
        if (izw[w] == s_iz) {
            float4 v = *(const float4*)&Pb[(size_t)w * CC + q * 4];
            int ix = ixw[w];
            int cb = q * 4;
            atomicAdd(&acc[(cb + 0) * (NXx + 1) + ix], v.x);
            atomicAdd(&acc[(cb + 1) * (NXx + 1) + ix], v.y);
            atomicAdd(&acc[(cb + 2) * (NXx + 1) + ix], v.z);
            atomicAdd(&acc[(cb + 3) * (NXx + 1) + ix], v.w);
        }
    }
    __syncthreads();

    // owner 0 (the common case) overwrites its zero-filled row in out;
    // later owners (collisions, never in practice) park in S for the fixup.
    bool owner0 = (s_k == 0);
    for (int i = t; i < CG8 * (NXx / 4); i += 256) {
        int c = i / (NXx / 4), q = i - c * (NXx / 4);
        int base = c * (NXx + 1) + q * 4;
        float4 vv;
        vv.x = acc[base + 0];
        vv.y = acc[base + 1];
        vv.z = acc[base + 2];
        vv.w = acc[base + 3];
        if (owner0) {
            float* orow = out + (((size_t)(b * CC + cg * CG8 + c)) * NZz + s_iz) * NXx;
            ((float4*)orow)[q] = vv;
        } else {
            float* Srow = S + ((size_t)bd * CC + cg * CG8 + c) * NXx;
            ((float4*)Srow)[q] = vv;
        }
    }
}

// ---------- Kernel C: dormant collision/overflow fixup (early-exits) ----------
__global__ __launch_bounds__(256) void lss_fixup(
    const float* __restrict__ S, const int* __restrict__ izd,
    const int* __restrict__ rowcnt8, const int* __restrict__ dlist8,
    const float* __restrict__ P,
    const int* __restrict__ ovcnt, const int* __restrict__ ovlist,
    float* __restrict__ out)
{
    int b = blockIdx.x;
    int t = threadIdx.x;

    // collision merge: one thread per (iz, cg) pair with n > 1 (never in practice)
    for (int pair = t; pair < NZz * 8; pair += 256) {
        int n = rowcnt8[b * NZz * 8 + pair];
        if (n <= 1) continue;
        int iz = pair >> 3, cg = pair & 7;
        const int* dl = dlist8 + (size_t)(b * NZz * 8 + pair) * DCAP;
        if (n <= DCAP) {
            for (int k = 1; k < n; ++k) {
                int d = dl[k];
                for (int c = 0; c < CG8; ++c) {
                    const float* Srow = S + ((size_t)(b * DD + d) * CC + cg * CG8 + c) * NXx;
                    float* orow = out + (((size_t)(b * CC + cg * CG8 + c)) * NZz + iz) * NXx;
                    for (int ix = 0; ix < NXx; ++ix) atomicAdd(&orow[ix], Srow[ix]);
                }
            }
        } else {
            int owner0 = dl[0];
            for (int d = 0; d < DD; ++d) {
                if (izd[b * DD + d] == iz && d != owner0) {
                    for (int c = 0; c < CG8; ++c) {
                        const float* Srow = S + ((size_t)(b * DD + d) * CC + cg * CG8 + c) * NXx;
                        float* orow = out + (((size_t)(b * CC + cg * CG8 + c)) * NZz + iz) * NXx;
                        for (int ix = 0; ix < NXx; ++ix) atomicAdd(&orow[ix], Srow[ix]);
                    }
                }
            }
        }
    }

    // dormant generic overflow fixup (entries with iz != owner's s_iz)
    if (b == 0 && t == 0) {
        int nov = *ovcnt;
        if (nov > OVCAP) nov = OVCAP;
        for (int k = 0; k < nov; ++k) {
            int ent = ovlist[k];
            int eb  = (ent >> 29) & 7;
            int ed  = (ent >> 23) & 63;
            int ew  = (ent >> 16) & 127;
            int eix = (ent >> 8) & 255;
            int eiz = ent & 255;
            for (int c = 0; c < CC; ++c) {
                size_t o = (((size_t)(eb * CC + c)) * NZz + eiz) * NXx + eix;
                atomicAdd(&out[o], P[(((size_t)eb * DD + ed) * FWw + ew) * CC + c]);
            }
        }
    }
}

extern "C" void kernel_launch(void* const* d_in, const int* in_sizes, int n_in,
                              void* d_out, int out_size, void* d_ws, size_t ws_size,
                              hipStream_t stream)
{
    const float* x          = (const float*)d_in[0];
    const float* intrins    = (const float*)d_in[1];
    const float* post_rots  = (const float*)d_in[2];
    const float* post_trans = (const float*)d_in[3];
    float* out = (float*)d_out;

    int B = in_sizes[0] / (NCH * (int)PLANE);

    size_t off = 0;
    auto alloc = [&](size_t bytes) {
        void* p = (char*)d_ws + off;
        off = (off + bytes + 255) & ~(size_t)255;
        return p;
    };
    float* P       = (float*)alloc((size_t)B * NE * CC * sizeof(float));       // 3.7 MB
    int*   V       = (int*)  alloc((size_t)B * NE * sizeof(int));
    float* S       = (float*)alloc((size_t)B * DD * CC * NXx * sizeof(float)); // 8.4 MB (dormant)
    int*   izd     = (int*)  alloc((size_t)B * DD * sizeof(int));
    int*   rowcnt8 = (int*)  alloc((size_t)B * NZz * 8 * sizeof(int));
    int*   dlist8  = (int*)  alloc((size_t)B * NZz * 8 * DCAP * sizeof(int));
    int*   ovcnt   = (int*)  alloc(256);
    int*   ovlist  = (int*)  alloc((size_t)OVCAP * sizeof(int));

    int out_quads = out_size / 4;

    lss_colpool<<<B * FWw, 256, 0, stream>>>(x, intrins, post_rots, post_trans,
                                             P, V, rowcnt8, ovcnt, out, out_quads);
    lss_rowbuild<<<B * DD * 8, 256, 0, stream>>>(P, V, S, izd, rowcnt8, dlist8,
                                                 ovcnt, ovlist, out);
    lss_fixup<<<B, 256, 0, stream>>>(S, izd, rowcnt8, dlist8, P, ovcnt, ovlist, out);
}